// Round 2
// baseline (501.889 us; speedup 1.0000x reference)
//
#include <hip/hip_runtime.h>

// FullyAdjacent rewiring: output is [2, G*N*N] int32, flattened.
//   rows half: out[j]        = (j % N^2) / N      (j in [0, half))
//   cols half: out[half + i] = i % N              (i in [0, half))
// N = in_sizes[2] (batch length), half = out_size/2 (G baked in by harness).
// Pure store-bound kernel: one 16B vector (4 consecutive int32) per thread.

typedef int v4i __attribute__((ext_vector_type(4)));  // clang vector: OK for nontemporal builtin

__global__ __launch_bounds__(256) void fa_pow2_kernel(
    int* __restrict__ out,
    long long n,        // total int32 elements
    long long half,     // n/2, guaranteed multiple of 4
    int shiftN,         // log2(N)
    int maskN)          // N-1
{
    long long i4 = (long long)blockIdx.x * blockDim.x + threadIdx.x;
    long long j = i4 << 2;              // int32 index of this lane's group
    if (j >= n) return;
    v4i v;
    if (j < half) {
        // rows: (j % N^2)/N == (j >> shiftN) & maskN for pow2 N.
        // Constant across the 4-group since 4 | N.
        int r = (int)((j >> shiftN) & (long long)maskN);
        v = (v4i){r, r, r, r};
    } else {
        // cols: (j - half) % N; no wrap inside the 4-group since 4 | N.
        int c = (int)((j - half) & (long long)maskN);
        v = (v4i){c, c + 1, c + 2, c + 3};
    }
    __builtin_nontemporal_store(v, (v4i*)(out + j));
}

// Fallback for non-pow2 N or unaligned sizes (not expected for this problem).
__global__ __launch_bounds__(256) void fa_generic_kernel(
    int* __restrict__ out, long long n, long long half, long long N)
{
    long long j = (long long)blockIdx.x * blockDim.x + threadIdx.x;
    if (j >= n) return;
    long long NN = N * N;
    int val;
    if (j < half) val = (int)((j % NN) / N);
    else          val = (int)((j - half) % N);
    out[j] = val;
}

extern "C" void kernel_launch(void* const* d_in, const int* in_sizes, int n_in,
                              void* d_out, int out_size, void* d_ws, size_t ws_size,
                              hipStream_t stream) {
    (void)d_in; (void)d_ws; (void)ws_size;
    int* out = (int*)d_out;
    long long n = (long long)out_size;
    long long half = n / 2;
    long long N = (n_in >= 3) ? (long long)in_sizes[2] : 4096;  // batch length

    bool pow2 = (N > 0) && ((N & (N - 1)) == 0);
    bool aligned = (n % 4 == 0) && (half % 4 == 0) && (N % 4 == 0);

    if (pow2 && aligned) {
        int shiftN = 0;
        while ((1LL << shiftN) < N) ++shiftN;
        int maskN = (int)(N - 1);
        long long n4 = n >> 2;
        int block = 256;
        long long grid = (n4 + block - 1) / block;
        fa_pow2_kernel<<<(dim3)(unsigned)grid, block, 0, stream>>>(
            out, n, half, shiftN, maskN);
    } else {
        int block = 256;
        long long grid = (n + block - 1) / block;
        fa_generic_kernel<<<(dim3)(unsigned)grid, block, 0, stream>>>(
            out, n, half, N);
    }
}

// Round 3
// 501.009 us; speedup vs baseline: 1.0018x; 1.0018x over previous
//
#include <hip/hip_runtime.h>

// FullyAdjacent rewiring: output is [2, G*N*N] int32, flattened.
//   rows half: out[j]        = (j % N^2) / N      (j in [0, half))
//   cols half: out[half + i] = i % N              (i in [0, half))
// N = in_sizes[2] (batch length), half = out_size/2 (G baked in by harness).
// Pure store-bound kernel: one 16B vector (4 consecutive int32) per thread.
// Round 2: plain (cached) stores — nontemporal bypassed L2 write-coalescing
// and ran at 1.07 TB/s vs memset's 6.2 TB/s. Also 32-bit indexing (out_size
// is an int, so all indices fit in 32 bits).

typedef int v4i __attribute__((ext_vector_type(4)));

__global__ __launch_bounds__(256) void fa_pow2_kernel(
    int* __restrict__ out,
    unsigned n,         // total int32 elements (fits: out_size is int)
    unsigned half,      // n/2, multiple of 4
    int shiftN,         // log2(N)
    int maskN)          // N-1
{
    unsigned i4 = blockIdx.x * blockDim.x + threadIdx.x;
    unsigned j = i4 << 2;               // int32 index of this lane's group
    if (j >= n) return;
    v4i v;
    if (j < half) {
        // rows: (j % N^2)/N == (j >> shiftN) & maskN for pow2 N.
        // Constant across the 4-group since 4 | N.
        int r = (int)((j >> shiftN) & (unsigned)maskN);
        v = (v4i){r, r, r, r};
    } else {
        // cols: (j - half) % N; no wrap inside the 4-group since 4 | N.
        int c = (int)((j - half) & (unsigned)maskN);
        v = (v4i){c, c + 1, c + 2, c + 3};
    }
    *(v4i*)(out + j) = v;   // plain global_store_dwordx4, L2-cached
}

// Fallback for non-pow2 N or unaligned sizes (not expected for this problem).
__global__ __launch_bounds__(256) void fa_generic_kernel(
    int* __restrict__ out, long long n, long long half, long long N)
{
    long long j = (long long)blockIdx.x * blockDim.x + threadIdx.x;
    if (j >= n) return;
    long long NN = N * N;
    int val;
    if (j < half) val = (int)((j % NN) / N);
    else          val = (int)((j - half) % N);
    out[j] = val;
}

extern "C" void kernel_launch(void* const* d_in, const int* in_sizes, int n_in,
                              void* d_out, int out_size, void* d_ws, size_t ws_size,
                              hipStream_t stream) {
    (void)d_in; (void)d_ws; (void)ws_size;
    int* out = (int*)d_out;
    long long n = (long long)out_size;
    long long half = n / 2;
    long long N = (n_in >= 3) ? (long long)in_sizes[2] : 4096;  // batch length

    bool pow2 = (N > 0) && ((N & (N - 1)) == 0);
    bool aligned = (n % 4 == 0) && (half % 4 == 0) && (N % 4 == 0);

    if (pow2 && aligned) {
        int shiftN = 0;
        while ((1LL << shiftN) < N) ++shiftN;
        int maskN = (int)(N - 1);
        long long n4 = n >> 2;
        int block = 256;
        long long grid = (n4 + block - 1) / block;
        fa_pow2_kernel<<<(dim3)(unsigned)grid, block, 0, stream>>>(
            out, (unsigned)n, (unsigned)half, shiftN, maskN);
    } else {
        int block = 256;
        long long grid = (n + block - 1) / block;
        fa_generic_kernel<<<(dim3)(unsigned)grid, block, 0, stream>>>(
            out, n, half, N);
    }
}